// Round 24
// baseline (1178.600 us; speedup 1.0000x reference)
//
#include <hip/hip_runtime.h>

#define DEVFN __device__ __forceinline__

static inline int ceil_div(int a, int b) { return (a + b - 1) / b; }

typedef __attribute__((ext_vector_type(8))) short         bf16x8;  // 8 bf16 = 4 VGPR
typedef __attribute__((ext_vector_type(4))) float         f32x4;
typedef __attribute__((ext_vector_type(8))) unsigned short u16x8;
typedef unsigned short us;

DEVFN us f2bf(float x) {           // RNE float->bf16 (finite inputs)
    unsigned u = __float_as_uint(x);
    unsigned r = ((u >> 16) & 1u) + 0x7fffu;
    return (us)((u + r) >> 16);
}
DEVFN float bf2f(us h) { return __uint_as_float(((unsigned)h) << 16); }

// ---------------------------------------------------------------------------
// DPP-based 64-lane max reduction step for a packed double key.
// ---------------------------------------------------------------------------
template<int CTRL>
DEVFN double dpp_max_step(double v)
{
    int lo = __double2loint(v), hi = __double2hiint(v);
    int tlo = __builtin_amdgcn_update_dpp(lo, lo, CTRL, 0xF, 0xF, false);
    int thi = __builtin_amdgcn_update_dpp(hi, hi, CTRL, 0xF, 0xF, false);
    return fmax(v, __hiloint2double(thi, tlo));
}

// ---------------------------------------------------------------------------
// Multi-wave farthest point sampling body (templated on thread count NT).
// Per step: per-lane candidate update (PPL = N/NT elems) + per-wave DPP max;
// lane-63s deposit wave keys into a ping-pong slot set; one barrier; all
// lanes tree-reduce the NW slot keys (broadcast reads). Packed key
// (dist_bits<<32 | ~idx) max is exact & order-independent -> identical
// indices for any NT. Distance arithmetic exact fp32 (no FMA contraction).
// ---------------------------------------------------------------------------
template<int N, int NT>
DEVFN void fps_body(const float* __restrict__ p, int MS,
                    int* __restrict__ oidx, float* __restrict__ onx,
                    float4* sp, double* kslots /* [2*NT/64] */)
{
    constexpr int PPL = N / NT;
    constexpr int NW  = NT / 64;
    const int tid = threadIdx.x;
    float px[PPL], py[PPL], pz[PPL], dd[PPL];
    unsigned lo[PPL];
    #pragma unroll
    for (int j = 0; j < PPL; ++j) {
        int idx = tid + NT * j;
        px[j] = p[idx*3+0]; py[j] = p[idx*3+1]; pz[j] = p[idx*3+2];
        sp[idx] = make_float4(px[j], py[j], pz[j], 0.f);
        dd[j] = 1e10f;
        lo[j] = ~(unsigned)idx;
    }
    __syncthreads();
    int far = 0;
    for (int s = 0; s < MS; ++s) {
        float4 c4 = sp[far];                      // uniform-address broadcast read
        if (tid == 0) {
            oidx[s] = far;
            onx[s*3+0] = c4.x; onx[s*3+1] = c4.y; onx[s*3+2] = c4.z;
        }
        double cand[PPL];
        #pragma unroll
        for (int j = 0; j < PPL; ++j) {
            float dx = __fsub_rn(px[j], c4.x);
            float dy = __fsub_rn(py[j], c4.y);
            float dz = __fsub_rn(pz[j], c4.z);
            float d  = __fadd_rn(__fadd_rn(__fmul_rn(dx,dx), __fmul_rn(dy,dy)),
                                 __fmul_rn(dz,dz));
            float nd = fminf(dd[j], d);
            dd[j] = nd;
            cand[j] = __hiloint2double(__float_as_int(nd), (int)lo[j]);
        }
        #pragma unroll
        for (int st = PPL/2; st > 0; st >>= 1)
            #pragma unroll
            for (int j = 0; j < PPL; ++j)
                if (j < st) cand[j] = fmax(cand[j], cand[j + st]);
        double v = cand[0];
        v = dpp_max_step<0xB1>(v);    // quad_perm xor1
        v = dpp_max_step<0x4E>(v);    // quad_perm xor2
        v = dpp_max_step<0x124>(v);   // row_ror:4
        v = dpp_max_step<0x128>(v);   // row_ror:8
        v = dpp_max_step<0x142>(v);   // row_bcast15
        v = dpp_max_step<0x143>(v);   // row_bcast31 -> lane 63 has wave max
        if ((tid & 63) == 63) kslots[(s & 1)*NW + (tid >> 6)] = v;
        __syncthreads();
        const double* ks = kslots + (s & 1)*NW;
        double kk[NW];
        #pragma unroll
        for (int q = 0; q < NW; ++q) kk[q] = ks[q];
        #pragma unroll
        for (int st = NW/2; st > 0; st >>= 1)
            #pragma unroll
            for (int q = 0; q < NW; ++q)
                if (q < st) kk[q] = fmax(kk[q], kk[q + st]);
        far = (int)(~(unsigned)__double2loint(kk[0]));
    }
}

// ---------------------------------------------------------------------------
// Weight-split job table (8 jobs), processed by piggyback blocks (512 thr).
// ---------------------------------------------------------------------------
struct WJobs {
    const float* src[8];
    us* wh[8];
    us* wl[8];
    int CItot[8], CO[8], CIpad[8], ro[8];
    int blk_off[9];          // cumulative block offsets (512-thread granularity)
};

// ---------------------------------------------------------------------------
// FUSED fps1 (8-wave, 512 threads) + weight-split piggyback.
// ---------------------------------------------------------------------------
template<int N>
__global__ __launch_bounds__(512) void fps8_wprep_kernel(
    const float* __restrict__ xyz, int M,
    int* __restrict__ out_idx, float* __restrict__ nxout,
    int nfps, WJobs jobs)
{
    __shared__ float4 sp[N];
    __shared__ double kslots[16];
    if ((int)blockIdx.x < nfps) {
        int b = blockIdx.x;
        fps_body<N, 512>(xyz + (size_t)b * N * 3, M,
                         out_idx + (size_t)b * M, nxout + (size_t)b * M * 3,
                         sp, kslots);
        return;
    }
    int wb = blockIdx.x - nfps;
    int j = 0;
    while (wb >= jobs.blk_off[j+1]) ++j;
    int t = (wb - jobs.blk_off[j]) * 512 + threadIdx.x;
    int CIpad = jobs.CIpad[j], CO = jobs.CO[j];
    if (t >= CIpad * CO) return;
    int co = t / CIpad, ci = t % CIpad;
    int src = ci + jobs.ro[j];
    float v = (src < jobs.CItot[j]) ? jobs.src[j][(size_t)src * CO + co] : 0.f;
    us h = f2bf(v);
    jobs.wh[j][t] = h;
    jobs.wl[j][t] = f2bf(v - bf2f(h));
}

// ---------------------------------------------------------------------------
// Ball query (standalone; used for SA1 only).
// ---------------------------------------------------------------------------
__global__ void ballquery_kernel(const float* __restrict__ xyz,
                                 const float* __restrict__ new_xyz,
                                 int* __restrict__ gi,
                                 int B, int N, int M, int K, float r2)
{
    int t = blockIdx.x * blockDim.x + threadIdx.x;
    if (t >= B * M) return;
    int b = t / M;
    const float* p = xyz + (size_t)b * N * 3;
    float cx = new_xyz[t*3+0], cy = new_xyz[t*3+1], cz = new_xyz[t*3+2];
    int* out = gi + (size_t)t * K;
    int cnt = 0, first = 0;
    bool havefirst = false;
    for (int i = 0; i < N; ++i) {
        float dx = __fsub_rn(p[i*3+0], cx);
        float dy = __fsub_rn(p[i*3+1], cy);
        float dz = __fsub_rn(p[i*3+2], cz);
        float d  = __fadd_rn(__fadd_rn(__fmul_rn(dx,dx), __fmul_rn(dy,dy)),
                             __fmul_rn(dz,dz));
        if (d <= r2) {
            if (!havefirst) { first = i; havefirst = true; }
            out[cnt++] = i;
            if (cnt == K) break;
        }
    }
    for (; cnt < K; ++cnt) out[cnt] = first;
}

DEVFN float f4_elem(const float4& v, int u) {
    return u == 0 ? v.x : u == 1 ? v.y : u == 2 ? v.z : v.w;
}

// ===========================================================================
// SA1 stage A (fp32 gather+center+layer1 -> split-bf16) WITH fps2 piggyback
// (fps2 runs the 4-wave body: NT=256, N=512, 128 steps).
// ===========================================================================
__global__ __launch_bounds__(256) void sa1_l1_fps2_kernel(
    const float* __restrict__ xyz, const float* __restrict__ feats,
    const float* __restrict__ new_xyz /* nx1 */, const int* __restrict__ gi,
    const float* __restrict__ w, const float* __restrict__ bias,
    us* __restrict__ oh, us* __restrict__ ol,
    int row0, int nb_main, int fps_on,
    int* __restrict__ fps2, float* __restrict__ nx2)
{
    __shared__ float4 sp[512];
    __shared__ double kslots[8];
    if ((int)blockIdx.x >= nb_main) {
        if (!fps_on) return;
        const int b = blockIdx.x - nb_main;
        fps_body<512, 256>(new_xyz + (size_t)b * 512 * 3, 128,
                           fps2 + (size_t)b * 128, nx2 + (size_t)b * 128 * 3,
                           sp, kslots);
        return;
    }
    // ---------------- sa_l1 role: SA1 (CF=3, CO=64, KPTS=32, N=1024, M=512)
    constexpr int CF = 3, CO = 64, KPTS = 32, N = 1024, M = 512, WCH = 16;
    const int lane = threadIdx.x & 63;
    const int wv   = __builtin_amdgcn_readfirstlane(threadIdx.x >> 6);
    const int rl   = blockIdx.x * 64 + lane;
    const int row  = row0 + rl;
    const int cent = row / KPTS;
    const int b    = cent / M;
    const int idx  = gi[row];
    const float* pp  = xyz + ((size_t)b*N + idx)*3;
    const float* cc3 = new_xyz + (size_t)cent*3;
    float a0 = __fsub_rn(pp[0], cc3[0]);
    float a1 = __fsub_rn(pp[1], cc3[1]);
    float a2 = __fsub_rn(pp[2], cc3[2]);
    const float* frow = feats + ((size_t)b*N + idx)*CF;
    float f0 = frow[0], f1v = frow[1], f2v = frow[2];
    const float* wcol = w + wv*WCH;
    const float* bcol = bias + wv*WCH;
    float acc[WCH];
    #pragma unroll
    for (int j = 0; j < WCH; ++j) {
        float a = bcol[j];
        a += a0 * wcol[0*CO + j];
        a += a1 * wcol[1*CO + j];
        a += a2 * wcol[2*CO + j];
        a += f0 * wcol[3*CO + j];
        a += f1v * wcol[4*CO + j];
        a += f2v * wcol[5*CO + j];
        acc[j] = a;
    }
    #pragma unroll
    for (int j8 = 0; j8 < WCH; j8 += 8) {
        u16x8 hv, lv;
        #pragma unroll
        for (int u = 0; u < 8; ++u) {
            float v = fmaxf(acc[j8+u], 0.f);
            us h = f2bf(v);
            hv[u] = h;
            lv[u] = f2bf(v - bf2f(h));
        }
        size_t o = (size_t)rl*CO + wv*WCH + j8;
        *(u16x8*)(&oh[o]) = hv;
        *(u16x8*)(&ol[o]) = lv;
    }
}

// ===========================================================================
// SA1 layer 2 MFMA (64->64, NTILE=4, MROW=4) WITH ballquery2 piggyback.
// ===========================================================================
__global__ __launch_bounds__(256) void sa1_l2_bq2_kernel(
    const us* __restrict__ ah, const us* __restrict__ al,
    const us* __restrict__ wh, const us* __restrict__ wl,
    const float* __restrict__ bias,
    us* __restrict__ oh, us* __restrict__ ol,
    int nb_main, int bq_on,
    const float* __restrict__ nx1, const float* __restrict__ nx2,
    int* __restrict__ gi2)
{
    if ((int)blockIdx.x >= nb_main) {
        if (!bq_on) return;
        int t = (blockIdx.x - nb_main) * 256 + threadIdx.x;
        if (t >= 32 * 128) return;
        constexpr int N = 512, M = 128, K = 64;
        const float r2 = (float)(0.4*0.4);
        int b = t / M;
        const float* p = nx1 + (size_t)b * N * 3;
        float cx = nx2[t*3+0], cy = nx2[t*3+1], cz = nx2[t*3+2];
        int* out = gi2 + (size_t)t * K;
        int cnt = 0, first = 0;
        bool havefirst = false;
        for (int i = 0; i < N; ++i) {
            float dx = __fsub_rn(p[i*3+0], cx);
            float dy = __fsub_rn(p[i*3+1], cy);
            float dz = __fsub_rn(p[i*3+2], cz);
            float d  = __fadd_rn(__fadd_rn(__fmul_rn(dx,dx), __fmul_rn(dy,dy)),
                                 __fmul_rn(dz,dz));
            if (d <= r2) {
                if (!havefirst) { first = i; havefirst = true; }
                out[cnt++] = i;
                if (cnt == K) break;
            }
        }
        for (; cnt < K; ++cnt) out[cnt] = first;
        return;
    }
    // ---------------- mfma 64->64 role (CI=64, CO=64, NTILE=4, MROW=4)
    constexpr int CI = 64, CO = 64, KT = 2, NTILE = 4, MROW = 4;
    const int wid  = threadIdx.x >> 6;
    const int lane = threadIdx.x & 63;
    const int m    = lane & 15;
    const int kg   = lane >> 4;
    const int blockrow = blockIdx.x * (64 * MROW);
    bf16x8 Ahf[MROW * KT], Alf[MROW * KT];
    #pragma unroll
    for (int t = 0; t < MROW; ++t) {
        const us* arh = ah + (size_t)(blockrow + t*64 + wid*16 + m) * CI + kg * 8;
        const us* arl = al + (size_t)(blockrow + t*64 + wid*16 + m) * CI + kg * 8;
        #pragma unroll
        for (int kt = 0; kt < KT; ++kt) {
            Ahf[t*KT + kt] = *(const bf16x8*)(arh + kt*32);
            Alf[t*KT + kt] = *(const bf16x8*)(arl + kt*32);
        }
    }
    #pragma unroll
    for (int nt = 0; nt < NTILE; ++nt) {
        f32x4 acc[MROW];
        #pragma unroll
        for (int t = 0; t < MROW; ++t) acc[t] = (f32x4){0.f, 0.f, 0.f, 0.f};
        const us* wbh = wh + (size_t)(nt*16 + m) * CI + kg * 8;
        const us* wbl = wl + (size_t)(nt*16 + m) * CI + kg * 8;
        #pragma unroll
        for (int kt = 0; kt < KT; ++kt) {
            bf16x8 Bh = *(const bf16x8*)(wbh + kt*32);
            bf16x8 Bl = *(const bf16x8*)(wbl + kt*32);
            #pragma unroll
            for (int t = 0; t < MROW; ++t) {
                acc[t] = __builtin_amdgcn_mfma_f32_16x16x32_bf16(Ahf[t*KT+kt], Bh, acc[t], 0, 0, 0);
                acc[t] = __builtin_amdgcn_mfma_f32_16x16x32_bf16(Ahf[t*KT+kt], Bl, acc[t], 0, 0, 0);
                acc[t] = __builtin_amdgcn_mfma_f32_16x16x32_bf16(Alf[t*KT+kt], Bh, acc[t], 0, 0, 0);
            }
        }
        int dcol = nt*16 + m;
        float bv = bias[dcol];
        #pragma unroll
        for (int t = 0; t < MROW; ++t)
            #pragma unroll
            for (int r = 0; r < 4; ++r) {
                float v = fmaxf(acc[t][r] + bv, 0.f);
                size_t o = (size_t)(blockrow + t*64 + wid*16 + kg*4 + r) * CO + dcol;
                us h = f2bf(v);
                oh[o] = h;
                ol[o] = f2bf(v - bf2f(h));
            }
    }
}

// ---------------------------------------------------------------------------
// MFMA layer with column tiling + MROW row-tiles + NCOL column-pairing.
// OUTMODE: 0 = split-bf16 out (piggyback: zero ofp on last y-slice if set),
//          1 = fp32 out, 2 = maxpool(KPTS)->fp32,
//          3 = maxpool(KPTS)->split-bf16 (stride CO),
//          4 = maxpool(64)->split-bf16 into g3 (stride 288, col offset 3;
//              blockIdx.y==1 blocks fill g3 xyz/pad cols from ofp(=nx2)),
//          5 = per-block max(64 rows) -> atomicMax fp32 (batch = 128 rows).
// ---------------------------------------------------------------------------
template<int CI, int CO, int NTILE, int MROW, int KPTS, int OUTMODE, int NCOL>
__global__ __launch_bounds__(256) void mfma_layer_kernel(
    const us* __restrict__ ah, const us* __restrict__ al,
    const us* __restrict__ wh, const us* __restrict__ wl,
    const float* __restrict__ bias,
    us* __restrict__ oh, us* __restrict__ ol,
    float* __restrict__ ofp, int rowbase)
{
    constexpr int KT = CI / 32;
    static_assert(KT * MROW <= 18, "A-preload register budget");
    static_assert(NTILE % NCOL == 0, "column pairing");
    __shared__ float partial[4][OUTMODE >= 2 ? MROW : 1][OUTMODE >= 2 ? 16*NTILE : 1];

    if constexpr (OUTMODE == 0) {
        if (ofp != nullptr && blockIdx.y == gridDim.y - 1) {
            int i = (blockIdx.x * 256 + threadIdx.x) * 4;
            if (i < 32*1024) {
                ofp[i+0] = 0.f; ofp[i+1] = 0.f; ofp[i+2] = 0.f; ofp[i+3] = 0.f;
            }
            return;
        }
    }
    if constexpr (OUTMODE == 4) {
        if (blockIdx.y == 1) {
            int t = blockIdx.x * 256 + threadIdx.x;
            if (t < 4096 * 32) {
                int row = t >> 5, k = t & 31;
                float v = (k < 3) ? ofp[row*3 + k] : 0.f;
                int col = (k < 3) ? k : 259 + (k - 3);
                size_t o = (size_t)row * 288 + col;
                us h = f2bf(v);
                oh[o] = h; ol[o] = f2bf(v - bf2f(h));
            }
            return;
        }
    }

    const int wid  = threadIdx.x >> 6;
    const int lane = threadIdx.x & 63;
    const int m    = lane & 15;
    const int kg   = lane >> 4;
    const int blockrow = blockIdx.x * (64 * MROW);
    const int colbase  = blockIdx.y * (16 * NTILE);
    bf16x8 Ahf[MROW * KT], Alf[MROW * KT];
    #pragma unroll
    for (int t = 0; t < MROW; ++t) {
        const us* arh = ah + (size_t)(blockrow + t*64 + wid*16 + m) * CI + kg * 8;
        const us* arl = al + (size_t)(blockrow + t*64 + wid*16 + m) * CI + kg * 8;
        #pragma unroll
        for (int kt = 0; kt < KT; ++kt) {
            Ahf[t*KT + kt] = *(const bf16x8*)(arh + kt*32);
            Alf[t*KT + kt] = *(const bf16x8*)(arl + kt*32);
        }
    }
    #pragma unroll
    for (int ntg = 0; ntg < NTILE; ntg += NCOL) {
        f32x4 acc[MROW][NCOL];
        #pragma unroll
        for (int t = 0; t < MROW; ++t)
            #pragma unroll
            for (int c = 0; c < NCOL; ++c) acc[t][c] = (f32x4){0.f, 0.f, 0.f, 0.f};
        const us* wbh[NCOL];
        const us* wbl[NCOL];
        #pragma unroll
        for (int c = 0; c < NCOL; ++c) {
            wbh[c] = wh + (size_t)(colbase + (ntg + c)*16 + m) * CI + kg * 8;
            wbl[c] = wl + (size_t)(colbase + (ntg + c)*16 + m) * CI + kg * 8;
        }
        #pragma unroll
        for (int kt = 0; kt < KT; ++kt) {
            bf16x8 Bh[NCOL], Bl[NCOL];
            #pragma unroll
            for (int c = 0; c < NCOL; ++c) {
                Bh[c] = *(const bf16x8*)(wbh[c] + kt*32);
                Bl[c] = *(const bf16x8*)(wbl[c] + kt*32);
            }
            #pragma unroll
            for (int t = 0; t < MROW; ++t)
                #pragma unroll
                for (int c = 0; c < NCOL; ++c) {
                    acc[t][c] = __builtin_amdgcn_mfma_f32_16x16x32_bf16(Ahf[t*KT+kt], Bh[c], acc[t][c], 0, 0, 0);
                    acc[t][c] = __builtin_amdgcn_mfma_f32_16x16x32_bf16(Ahf[t*KT+kt], Bl[c], acc[t][c], 0, 0, 0);
                    acc[t][c] = __builtin_amdgcn_mfma_f32_16x16x32_bf16(Alf[t*KT+kt], Bh[c], acc[t][c], 0, 0, 0);
                }
        }
        #pragma unroll
        for (int c = 0; c < NCOL; ++c) {
            const int nt = ntg + c;
            int dcol = colbase + nt*16 + m;
            float bv = bias[dcol];
            #pragma unroll
            for (int t = 0; t < MROW; ++t) {
                float v[4];
                #pragma unroll
                for (int r = 0; r < 4; ++r) v[r] = fmaxf(acc[t][c][r] + bv, 0.f);
                if constexpr (OUTMODE == 0) {
                    #pragma unroll
                    for (int r = 0; r < 4; ++r) {
                        size_t o = (size_t)(blockrow + t*64 + wid*16 + kg*4 + r) * CO + dcol;
                        us h = f2bf(v[r]);
                        oh[o] = h;
                        ol[o] = f2bf(v[r] - bf2f(h));
                    }
                } else if constexpr (OUTMODE == 1) {
                    #pragma unroll
                    for (int r = 0; r < 4; ++r)
                        ofp[(size_t)(blockrow + t*64 + wid*16 + kg*4 + r) * CO + dcol] = v[r];
                } else {
                    float mx = fmaxf(fmaxf(v[0], v[1]), fmaxf(v[2], v[3]));
                    mx = fmaxf(mx, __shfl_xor(mx, 16));
                    mx = fmaxf(mx, __shfl_xor(mx, 32));
                    if (lane < 16) partial[wid][t][nt*16 + m] = mx;
                }
            }
        }
    }
    if constexpr (OUTMODE >= 2) {
        __syncthreads();
        for (int c = threadIdx.x; c < 16*NTILE; c += 256) {
            #pragma unroll
            for (int t = 0; t < MROW; ++t) {
                if constexpr (OUTMODE == 5) {
                    float mx = fmaxf(fmaxf(partial[0][t][c], partial[1][t][c]),
                                     fmaxf(partial[2][t][c], partial[3][t][c]));
                    int batch = (rowbase + blockrow + t*64) / 128;
                    atomicMax((int*)&ofp[(size_t)batch*CO + colbase + c],
                              __float_as_int(mx));
                } else if constexpr (KPTS == 64) {
                    float mx = fmaxf(fmaxf(partial[0][t][c], partial[1][t][c]),
                                     fmaxf(partial[2][t][c], partial[3][t][c]));
                    int cent = (rowbase + blockrow) / 64 + t;
                    if constexpr (OUTMODE == 2) {
                        ofp[(size_t)cent*CO + colbase + c] = mx;
                    } else if constexpr (OUTMODE == 4) {
                        size_t o = (size_t)cent*288 + 3 + colbase + c;
                        us h = f2bf(mx);
                        oh[o] = h; ol[o] = f2bf(mx - bf2f(h));
                    } else {
                        size_t o = (size_t)cent*CO + colbase + c;
                        us h = f2bf(mx);
                        oh[o] = h; ol[o] = f2bf(mx - bf2f(h));
                    }
                } else {               // KPTS == 32
                    int cent0 = (rowbase + blockrow) / 32 + t*2;
                    float v0 = fmaxf(partial[0][t][c], partial[1][t][c]);
                    float v1 = fmaxf(partial[2][t][c], partial[3][t][c]);
                    if constexpr (OUTMODE == 2) {
                        ofp[(size_t)cent0*CO + colbase + c]     = v0;
                        ofp[(size_t)(cent0+1)*CO + colbase + c] = v1;
                    } else {
                        size_t o0 = (size_t)cent0*CO + colbase + c;
                        size_t o1 = (size_t)(cent0+1)*CO + colbase + c;
                        us h0 = f2bf(v0), h1 = f2bf(v1);
                        oh[o0] = h0; ol[o0] = f2bf(v0 - bf2f(h0));
                        oh[o1] = h1; ol[o1] = f2bf(v1 - bf2f(h1));
                    }
                }
            }
        }
    }
}

// ---------------------------------------------------------------------------
// SA2 layer 1 as MFMA with per-lane GATHERED A rows (f1 split bf16) plus the
// 3-channel xyz part on the VALU in the epilogue.
// ---------------------------------------------------------------------------
template<int NTILE, int MROW>
__global__ __launch_bounds__(256) void mfma_sa2l1_kernel(
    const float* __restrict__ sxyz, const float* __restrict__ cxyz,
    const int* __restrict__ gi,
    const us* __restrict__ f1h, const us* __restrict__ f1l,
    const float* __restrict__ w,
    const us* __restrict__ wh, const us* __restrict__ wl,
    const float* __restrict__ bias,
    us* __restrict__ oh, us* __restrict__ ol,
    int rowbase)
{
    constexpr int CI = 128, CO = 128, KT = 4, KPTS = 64, M = 128, N = 512;
    const int wid  = threadIdx.x >> 6;
    const int lane = threadIdx.x & 63;
    const int m    = lane & 15;
    const int kg   = lane >> 4;
    const int blockrow = blockIdx.x * (64 * MROW);
    const int colbase  = blockIdx.y * (16 * NTILE);
    bf16x8 Ahf[MROW * KT], Alf[MROW * KT];
    #pragma unroll
    for (int t = 0; t < MROW; ++t) {
        int grow = rowbase + blockrow + t*64 + wid*16 + m;
        int cent = grow / KPTS;
        int b    = cent / M;
        int idx  = gi[grow];
        const us* arh = f1h + ((size_t)b*N + idx) * CI + kg * 8;
        const us* arl = f1l + ((size_t)b*N + idx) * CI + kg * 8;
        #pragma unroll
        for (int kt = 0; kt < KT; ++kt) {
            Ahf[t*KT + kt] = *(const bf16x8*)(arh + kt*32);
            Alf[t*KT + kt] = *(const bf16x8*)(arl + kt*32);
        }
    }
    float dx[MROW][4], dy[MROW][4], dz[MROW][4];
    #pragma unroll
    for (int t = 0; t < MROW; ++t)
        #pragma unroll
        for (int r = 0; r < 4; ++r) {
            int grow = rowbase + blockrow + t*64 + wid*16 + kg*4 + r;
            int cent = grow / KPTS;
            int b    = cent / M;
            int idx  = gi[grow];
            const float* pp = sxyz + ((size_t)b*N + idx)*3;
            const float* cc = cxyz + (size_t)cent*3;
            dx[t][r] = __fsub_rn(pp[0], cc[0]);
            dy[t][r] = __fsub_rn(pp[1], cc[1]);
            dz[t][r] = __fsub_rn(pp[2], cc[2]);
        }
    #pragma unroll
    for (int nt = 0; nt < NTILE; ++nt) {
        f32x4 acc[MROW];
        #pragma unroll
        for (int t = 0; t < MROW; ++t) acc[t] = (f32x4){0.f, 0.f, 0.f, 0.f};
        const us* wbh = wh + (size_t)(colbase + nt*16 + m) * CI + kg * 8;
        const us* wbl = wl + (size_t)(colbase + nt*16 + m) * CI + kg * 8;
        #pragma unroll
        for (int kt = 0; kt < KT; ++kt) {
            bf16x8 Bh = *(const bf16x8*)(wbh + kt*32);
            bf16x8 Bl = *(const bf16x8*)(wbl + kt*32);
            #pragma unroll
            for (int t = 0; t < MROW; ++t) {
                acc[t] = __builtin_amdgcn_mfma_f32_16x16x32_bf16(Ahf[t*KT+kt], Bh, acc[t], 0, 0, 0);
                acc[t] = __builtin_amdgcn_mfma_f32_16x16x32_bf16(Ahf[t*KT+kt], Bl, acc[t], 0, 0, 0);
                acc[t] = __builtin_amdgcn_mfma_f32_16x16x32_bf16(Alf[t*KT+kt], Bh, acc[t], 0, 0, 0);
            }
        }
        int dcol = colbase + nt*16 + m;
        float w0 = w[0*CO + dcol], w1 = w[1*CO + dcol], w2 = w[2*CO + dcol];
        float bv = bias[dcol];
        #pragma unroll
        for (int t = 0; t < MROW; ++t)
            #pragma unroll
            for (int r = 0; r < 4; ++r) {
                float v = acc[t][r] + bv + dx[t][r]*w0 + dy[t][r]*w1 + dz[t][r]*w2;
                v = fmaxf(v, 0.f);
                size_t o = (size_t)(blockrow + t*64 + wid*16 + kg*4 + r) * CO + dcol;
                us h = f2bf(v);
                oh[o] = h;
                ol[o] = f2bf(v - bf2f(h));
            }
    }
}

// ---------------------------------------------------------------------------
// Small-M FC GEMM: one thread per output element, no LDS, no barriers.
// ---------------------------------------------------------------------------
template<int RELU, int HASB>
__global__ __launch_bounds__(256) void fc_kernel(
    const float* __restrict__ A, const float* __restrict__ W,
    const float* __restrict__ bias, float* __restrict__ Cc,
    int Mr, int Nc, int Kd)
{
    int t = blockIdx.x * 256 + threadIdx.x;
    if (t >= Mr * Nc) return;
    int row = t / Nc, col = t % Nc;
    const float* a = A + (size_t)row * Kd;
    const float* w = W + col;
    float acc = 0.f;
    #pragma unroll 8
    for (int k = 0; k < Kd; ++k)
        acc += a[k] * w[(size_t)k * Nc];
    if (HASB) acc += bias[col];
    if (RELU) acc = fmaxf(acc, 0.f);
    Cc[t] = acc;
}

// ---------------------------------------------------------------------------
extern "C" void kernel_launch(void* const* d_in, const int* in_sizes, int n_in,
                              void* d_out, int out_size, void* d_ws, size_t ws_size,
                              hipStream_t stream)
{
    const float* xyz    = (const float*)d_in[0];
    const float* points = (const float*)d_in[1];
    const float* w1a = (const float*)d_in[2];  const float* b1a = (const float*)d_in[3];
    const float* w1b = (const float*)d_in[4];  const float* b1b = (const float*)d_in[5];
    const float* w1c = (const float*)d_in[6];  const float* b1c = (const float*)d_in[7];
    const float* w2a = (const float*)d_in[8];  const float* b2a = (const float*)d_in[9];
    const float* w2b = (const float*)d_in[10]; const float* b2b = (const float*)d_in[11];
    const float* w2c = (const float*)d_in[12]; const float* b2c = (const float*)d_in[13];
    const float* w3a = (const float*)d_in[14]; const float* b3a = (const float*)d_in[15];
    const float* w3b = (const float*)d_in[16]; const float* b3b = (const float*)d_in[17];
    const float* w3c = (const float*)d_in[18]; const float* b3c = (const float*)d_in[19];
    const float* lin1 = (const float*)d_in[20];
    const float* lin2 = (const float*)d_in[21];
    const float* clsw = (const float*)d_in[22];
    const float* clsb = (const float*)d_in[23];

    char* ws = (char*)d_ws;
    size_t off = 0;
    auto alloc = [&](size_t bytes) -> void* {
        void* p = ws + off;
        off += (bytes + 255) & ~(size_t)255;
        return p;
    };
    int*   fps1 = (int*)  alloc((size_t)32*512*4);
    float* nx1  = (float*)alloc((size_t)32*512*3*4);
    int*   gi1  = (int*)  alloc((size_t)32*512*32*4);
    int*   fps2 = (int*)  alloc((size_t)32*128*4);
    float* nx2  = (float*)alloc((size_t)32*128*3*4);
    int*   gi2  = (int*)  alloc((size_t)32*128*64*4);
    float* f3   = (float*)alloc((size_t)32*1024*4);
    float* fc1  = (float*)alloc((size_t)32*512*4);
    float* fc2  = (float*)alloc((size_t)32*256*4);

    // split weights (transposed [CO][CIpad], bf16 hi/lo)
    us* w1bh = (us*)alloc(64*64*2);     us* w1bl = (us*)alloc(64*64*2);
    us* w1ch = (us*)alloc(128*64*2);    us* w1cl = (us*)alloc(128*64*2);
    us* w2ah = (us*)alloc(128*128*2);   us* w2al = (us*)alloc(128*128*2);   // feats rows 3..130
    us* w2bh = (us*)alloc(128*128*2);   us* w2bl = (us*)alloc(128*128*2);
    us* w2ch = (us*)alloc(256*128*2);   us* w2cl = (us*)alloc(256*128*2);
    us* w3ah = (us*)alloc(256*288*2);   us* w3al = (us*)alloc(256*288*2);   // padded 259->288
    us* w3bh = (us*)alloc(512*256*2);   us* w3bl = (us*)alloc(512*256*2);
    us* w3ch = (us*)alloc(1024*512*2);  us* w3cl = (us*)alloc(1024*512*2);
    // SA1 output (split) = SA2 input feats (L2/L3-resident, 8.4 MB)
    us* f1h  = (us*)alloc((size_t)16384*128*2);
    us* f1l  = (us*)alloc((size_t)16384*128*2);
    // SA3 activations
    us* g3H  = (us*)alloc((size_t)4096*288*2);  us* g3L  = (us*)alloc((size_t)4096*288*2);
    us* h3aH = (us*)alloc((size_t)4096*256*2);  us* h3aL = (us*)alloc((size_t)4096*256*2);
    us* h3bH = (us*)alloc((size_t)4096*512*2);  us* h3bL = (us*)alloc((size_t)4096*512*2);

    // big split activation ping-pong buffers (hi/lo per side)
    size_t avail = (ws_size > off + 1024) ? (ws_size - off - 1024) : 0;
    size_t bufcap = avail / 4;
    if (bufcap > (size_t)67200000) bufcap = 67200000;   // 524288 rows x 64ch x 2B
    us* Ah = (us*)alloc(bufcap); us* Al = (us*)alloc(bufcap);
    us* Bh = (us*)alloc(bufcap); us* Bl = (us*)alloc(bufcap);

    // ---- weight-prep job table (runs as piggyback blocks inside fps1 launch)
    WJobs jobs;
    {
        const float* src[8] = { w1b, w1c, w2a, w2b, w2c, w3a, w3b, w3c };
        us* wh[8] = { w1bh, w1ch, w2ah, w2bh, w2ch, w3ah, w3bh, w3ch };
        us* wl[8] = { w1bl, w1cl, w2al, w2bl, w2cl, w3al, w3bl, w3cl };
        int CItot[8] = { 64, 64, 131, 128, 128, 259, 256, 512 };
        int CO[8]    = { 64, 128, 128, 128, 256, 256, 512, 1024 };
        int CIpad[8] = { 64, 64, 128, 128, 128, 288, 256, 512 };
        int ro[8]    = { 0, 0, 3, 0, 0, 0, 0, 0 };
        int cum = 0;
        for (int j = 0; j < 8; ++j) {
            jobs.src[j] = src[j]; jobs.wh[j] = wh[j]; jobs.wl[j] = wl[j];
            jobs.CItot[j] = CItot[j]; jobs.CO[j] = CO[j];
            jobs.CIpad[j] = CIpad[j]; jobs.ro[j] = ro[j];
            jobs.blk_off[j] = cum;
            cum += ceil_div(CIpad[j] * CO[j], 512);
        }
        jobs.blk_off[8] = cum;
    }

    // ---- SA1: N=1024 -> M=512, r=0.2, K=32, MLP 6->64->64->128
    fps8_wprep_kernel<1024><<<32 + jobs.blk_off[8], 512, 0, stream>>>(
        xyz, 512, fps1, nx1, 32, jobs);
    ballquery_kernel<<<ceil_div(32*512, 256), 256, 0, stream>>>(
        xyz, nx1, gi1, 32, 1024, 512, 32, (float)(0.2*0.2));
    {
        const int rows = 32*512*32;                     // 524288
        int ch = (int)((bufcap / (64*2)) & ~(size_t)1023);
        if (ch > rows) ch = rows;
        if (ch < 1024) ch = 1024;
        int first = 1;
        for (int r0 = 0; r0 < rows; r0 += ch) {
            int rc = rows - r0 < ch ? rows - r0 : ch;
            int nb1 = rc/64, nb2 = rc/256;
            sa1_l1_fps2_kernel<<<nb1 + (first ? 32 : 0), 256, 0, stream>>>(
                xyz, points, nx1, gi1, w1a, b1a, Ah, Al, r0, nb1, first, fps2, nx2);
            sa1_l2_bq2_kernel<<<nb2 + (first ? 16 : 0), 256, 0, stream>>>(
                Ah, Al, w1bh, w1bl, b1b, Bh, Bl, nb2, first, nx1, nx2, gi2);
            mfma_layer_kernel<64, 128, 8, 4, 32, 3, 1><<<dim3(nb2, 1), 256, 0, stream>>>(
                Bh, Bl, w1ch, w1cl, b1c, f1h, f1l, nullptr, r0);
            first = 0;
        }
    }

    // ---- SA2: N=512 -> M=128, r=0.4, K=64, MLP 131->128->128->256
    //      (L3 writes split-bf16 directly into g3; y=1 slice fills xyz/pad)
    {
        const int rows = 32*128*64;                     // 262144
        int ch = (int)((bufcap / (128*2)) & ~(size_t)1023);
        if (ch > rows) ch = rows;
        if (ch < 1024) ch = 1024;
        for (int r0 = 0; r0 < rows; r0 += ch) {
            int rc = rows - r0 < ch ? rows - r0 : ch;
            mfma_sa2l1_kernel<8, 2><<<dim3(rc/128, 1), 256, 0, stream>>>(
                nx1, nx2, gi2, f1h, f1l, w2a, w2ah, w2al, b2a, Ah, Al, r0);
            mfma_layer_kernel<128, 128, 8, 4, 0, 0, 1><<<dim3(rc/256, 1), 256, 0, stream>>>(
                Ah, Al, w2bh, w2bl, b2b, Bh, Bl, nullptr, 0);
            mfma_layer_kernel<128, 256, 16, 4, 64, 4, 1><<<dim3(rc/256, 2), 256, 0, stream>>>(
                Bh, Bl, w2ch, w2cl, b2c, g3H, g3L, (float*)nx2, r0);
        }
    }

    // ---- SA3 (group_all): g3 [4096][288] -> 288->256 -> 256->512 (zeroes f3
    //      on extra y-slice) -> 512->1024 + fused atomicMax rowmax -> f3
    mfma_layer_kernel<288, 256, 2, 1, 0, 0, 2><<<dim3(4096/64, 256/32), 256, 0, stream>>>(
        g3H, g3L, w3ah, w3al, b3a, h3aH, h3aL, nullptr, 0);
    mfma_layer_kernel<256, 512, 2, 2, 0, 0, 2><<<dim3(4096/128, 512/32 + 1), 256, 0, stream>>>(
        h3aH, h3aL, w3bh, w3bl, b3b, h3bH, h3bL, f3, 0);
    mfma_layer_kernel<512, 1024, 4, 1, 0, 5, 2><<<dim3(4096/64, 1024/64), 256, 0, stream>>>(
        h3bH, h3bL, w3ch, w3cl, b3c, nullptr, nullptr, f3, 0);

    // ---- FC head (fp32, thread-per-output latency-optimized)
    fc_kernel<1,0><<<ceil_div(32*512, 256), 256, 0, stream>>>(
        f3, lin1, nullptr, fc1, 32, 512, 1024);
    fc_kernel<1,0><<<ceil_div(32*256, 256), 256, 0, stream>>>(
        fc1, lin2, nullptr, fc2, 32, 256, 512);
    fc_kernel<0,1><<<ceil_div(32*40, 256), 256, 0, stream>>>(
        fc2, clsw, clsb, (float*)d_out, 32, 40, 256);
}

// Round 25
// 1163.645 us; speedup vs baseline: 1.0129x; 1.0129x over previous
//
#include <hip/hip_runtime.h>

#define DEVFN __device__ __forceinline__

static inline int ceil_div(int a, int b) { return (a + b - 1) / b; }

typedef __attribute__((ext_vector_type(8))) short         bf16x8;  // 8 bf16 = 4 VGPR
typedef __attribute__((ext_vector_type(4))) float         f32x4;
typedef __attribute__((ext_vector_type(8))) unsigned short u16x8;
typedef unsigned short us;

DEVFN us f2bf(float x) {           // RNE float->bf16 (finite inputs)
    unsigned u = __float_as_uint(x);
    unsigned r = ((u >> 16) & 1u) + 0x7fffu;
    return (us)((u + r) >> 16);
}
DEVFN float bf2f(us h) { return __uint_as_float(((unsigned)h) << 16); }

// ---------------------------------------------------------------------------
// DPP-based 64-lane max reduction step for a packed double key.
// ---------------------------------------------------------------------------
template<int CTRL>
DEVFN double dpp_max_step(double v)
{
    int lo = __double2loint(v), hi = __double2hiint(v);
    int tlo = __builtin_amdgcn_update_dpp(lo, lo, CTRL, 0xF, 0xF, false);
    int thi = __builtin_amdgcn_update_dpp(hi, hi, CTRL, 0xF, 0xF, false);
    return fmax(v, __hiloint2double(thi, tlo));
}

// ---------------------------------------------------------------------------
// 4-WAVE farthest point sampling body (R20/R22/R23 winner; 176 µs @ N=1024).
// Packed key (dist_bits<<32 | ~idx) max is exact -> identical indices.
// Distance arithmetic exact fp32 (no FMA contraction) to match numpy.
// ---------------------------------------------------------------------------
template<int N>
DEVFN void fps4_body(const float* __restrict__ p, int MS,
                     int* __restrict__ oidx, float* __restrict__ onx,
                     float4* sp, double* kslots)
{
    constexpr int PPL = N / 256;
    const int tid = threadIdx.x;
    float px[PPL], py[PPL], pz[PPL], dd[PPL];
    unsigned lo[PPL];
    #pragma unroll
    for (int j = 0; j < PPL; ++j) {
        int idx = tid + 256 * j;
        px[j] = p[idx*3+0]; py[j] = p[idx*3+1]; pz[j] = p[idx*3+2];
        sp[idx] = make_float4(px[j], py[j], pz[j], 0.f);
        dd[j] = 1e10f;
        lo[j] = ~(unsigned)idx;
    }
    __syncthreads();
    int far = 0;
    for (int s = 0; s < MS; ++s) {
        float4 c4 = sp[far];                      // uniform-address broadcast read
        if (tid == 0) {
            oidx[s] = far;
            onx[s*3+0] = c4.x; onx[s*3+1] = c4.y; onx[s*3+2] = c4.z;
        }
        double cand[PPL];
        #pragma unroll
        for (int j = 0; j < PPL; ++j) {
            float dx = __fsub_rn(px[j], c4.x);
            float dy = __fsub_rn(py[j], c4.y);
            float dz = __fsub_rn(pz[j], c4.z);
            float d  = __fadd_rn(__fadd_rn(__fmul_rn(dx,dx), __fmul_rn(dy,dy)),
                                 __fmul_rn(dz,dz));
            float nd = fminf(dd[j], d);
            dd[j] = nd;
            cand[j] = __hiloint2double(__float_as_int(nd), (int)lo[j]);
        }
        #pragma unroll
        for (int st = PPL/2; st > 0; st >>= 1)
            #pragma unroll
            for (int j = 0; j < PPL; ++j)
                if (j < st) cand[j] = fmax(cand[j], cand[j + st]);
        double v = cand[0];
        v = dpp_max_step<0xB1>(v);    // quad_perm xor1
        v = dpp_max_step<0x4E>(v);    // quad_perm xor2
        v = dpp_max_step<0x124>(v);   // row_ror:4
        v = dpp_max_step<0x128>(v);   // row_ror:8
        v = dpp_max_step<0x142>(v);   // row_bcast15
        v = dpp_max_step<0x143>(v);   // row_bcast31 -> lane 63 has wave max
        if ((tid & 63) == 63) kslots[(s & 1)*4 + (tid >> 6)] = v;
        __syncthreads();
        const double* ks = kslots + (s & 1)*4;
        double kx = fmax(fmax(ks[0], ks[1]), fmax(ks[2], ks[3]));
        far = (int)(~(unsigned)__double2loint(kx));
    }
}

// ---------------------------------------------------------------------------
// Weight-split job table (8 jobs), processed by piggyback blocks.
// ---------------------------------------------------------------------------
struct WJobs {
    const float* src[8];
    us* wh[8];
    us* wl[8];
    int CItot[8], CO[8], CIpad[8], ro[8];
    int blk_off[9];          // cumulative block offsets
};

// ---------------------------------------------------------------------------
// FUSED fps1 + weight-split.
// ---------------------------------------------------------------------------
template<int N>
__global__ __launch_bounds__(256) void fps4_wprep_kernel(
    const float* __restrict__ xyz, int M,
    int* __restrict__ out_idx, float* __restrict__ nxout,
    int nfps, WJobs jobs)
{
    __shared__ float4 sp[N];
    __shared__ double kslots[8];
    if ((int)blockIdx.x < nfps) {
        int b = blockIdx.x;
        fps4_body<N>(xyz + (size_t)b * N * 3, M,
                     out_idx + (size_t)b * M, nxout + (size_t)b * M * 3,
                     sp, kslots);
        return;
    }
    int wb = blockIdx.x - nfps;
    int j = 0;
    while (wb >= jobs.blk_off[j+1]) ++j;
    int t = (wb - jobs.blk_off[j]) * 256 + threadIdx.x;
    int CIpad = jobs.CIpad[j], CO = jobs.CO[j];
    if (t >= CIpad * CO) return;
    int co = t / CIpad, ci = t % CIpad;
    int src = ci + jobs.ro[j];
    float v = (src < jobs.CItot[j]) ? jobs.src[j][(size_t)src * CO + co] : 0.f;
    us h = f2bf(v);
    jobs.wh[j][t] = h;
    jobs.wl[j][t] = f2bf(v - bf2f(h));
}

// ---------------------------------------------------------------------------
// Ball query (standalone; used for SA1 only).
// ---------------------------------------------------------------------------
__global__ void ballquery_kernel(const float* __restrict__ xyz,
                                 const float* __restrict__ new_xyz,
                                 int* __restrict__ gi,
                                 int B, int N, int M, int K, float r2)
{
    int t = blockIdx.x * blockDim.x + threadIdx.x;
    if (t >= B * M) return;
    int b = t / M;
    const float* p = xyz + (size_t)b * N * 3;
    float cx = new_xyz[t*3+0], cy = new_xyz[t*3+1], cz = new_xyz[t*3+2];
    int* out = gi + (size_t)t * K;
    int cnt = 0, first = 0;
    bool havefirst = false;
    for (int i = 0; i < N; ++i) {
        float dx = __fsub_rn(p[i*3+0], cx);
        float dy = __fsub_rn(p[i*3+1], cy);
        float dz = __fsub_rn(p[i*3+2], cz);
        float d  = __fadd_rn(__fadd_rn(__fmul_rn(dx,dx), __fmul_rn(dy,dy)),
                             __fmul_rn(dz,dz));
        if (d <= r2) {
            if (!havefirst) { first = i; havefirst = true; }
            out[cnt++] = i;
            if (cnt == K) break;
        }
    }
    for (; cnt < K; ++cnt) out[cnt] = first;
}

DEVFN float f4_elem(const float4& v, int u) {
    return u == 0 ? v.x : u == 1 ? v.y : u == 2 ? v.z : v.w;
}

// ===========================================================================
// SA1 stage A (fp32 gather+center+layer1 -> split-bf16) WITH fps2 piggyback.
// ===========================================================================
__global__ __launch_bounds__(256) void sa1_l1_fps2_kernel(
    const float* __restrict__ xyz, const float* __restrict__ feats,
    const float* __restrict__ new_xyz /* nx1 */, const int* __restrict__ gi,
    const float* __restrict__ w, const float* __restrict__ bias,
    us* __restrict__ oh, us* __restrict__ ol,
    int row0, int nb_main, int fps_on,
    int* __restrict__ fps2, float* __restrict__ nx2)
{
    __shared__ float4 sp[512];
    __shared__ double kslots[8];
    if ((int)blockIdx.x >= nb_main) {
        if (!fps_on) return;
        const int b = blockIdx.x - nb_main;
        fps4_body<512>(new_xyz + (size_t)b * 512 * 3, 128,
                       fps2 + (size_t)b * 128, nx2 + (size_t)b * 128 * 3,
                       sp, kslots);
        return;
    }
    // ---------------- sa_l1 role: SA1 (CF=3, CO=64, KPTS=32, N=1024, M=512)
    constexpr int CF = 3, CO = 64, KPTS = 32, N = 1024, M = 512, WCH = 16;
    const int lane = threadIdx.x & 63;
    const int wv   = __builtin_amdgcn_readfirstlane(threadIdx.x >> 6);
    const int rl   = blockIdx.x * 64 + lane;
    const int row  = row0 + rl;
    const int cent = row / KPTS;
    const int b    = cent / M;
    const int idx  = gi[row];
    const float* pp  = xyz + ((size_t)b*N + idx)*3;
    const float* cc3 = new_xyz + (size_t)cent*3;
    float a0 = __fsub_rn(pp[0], cc3[0]);
    float a1 = __fsub_rn(pp[1], cc3[1]);
    float a2 = __fsub_rn(pp[2], cc3[2]);
    const float* frow = feats + ((size_t)b*N + idx)*CF;
    float f0 = frow[0], f1v = frow[1], f2v = frow[2];
    const float* wcol = w + wv*WCH;
    const float* bcol = bias + wv*WCH;
    float acc[WCH];
    #pragma unroll
    for (int j = 0; j < WCH; ++j) {
        float a = bcol[j];
        a += a0 * wcol[0*CO + j];
        a += a1 * wcol[1*CO + j];
        a += a2 * wcol[2*CO + j];
        a += f0 * wcol[3*CO + j];
        a += f1v * wcol[4*CO + j];
        a += f2v * wcol[5*CO + j];
        acc[j] = a;
    }
    #pragma unroll
    for (int j8 = 0; j8 < WCH; j8 += 8) {
        u16x8 hv, lv;
        #pragma unroll
        for (int u = 0; u < 8; ++u) {
            float v = fmaxf(acc[j8+u], 0.f);
            us h = f2bf(v);
            hv[u] = h;
            lv[u] = f2bf(v - bf2f(h));
        }
        size_t o = (size_t)rl*CO + wv*WCH + j8;
        *(u16x8*)(&oh[o]) = hv;
        *(u16x8*)(&ol[o]) = lv;
    }
}

// ===========================================================================
// SA1 layer 2 MFMA (64->64, NTILE=4, MROW=4) WITH ballquery2 piggyback.
// ===========================================================================
__global__ __launch_bounds__(256) void sa1_l2_bq2_kernel(
    const us* __restrict__ ah, const us* __restrict__ al,
    const us* __restrict__ wh, const us* __restrict__ wl,
    const float* __restrict__ bias,
    us* __restrict__ oh, us* __restrict__ ol,
    int nb_main, int bq_on,
    const float* __restrict__ nx1, const float* __restrict__ nx2,
    int* __restrict__ gi2)
{
    if ((int)blockIdx.x >= nb_main) {
        if (!bq_on) return;
        int t = (blockIdx.x - nb_main) * 256 + threadIdx.x;
        if (t >= 32 * 128) return;
        constexpr int N = 512, M = 128, K = 64;
        const float r2 = (float)(0.4*0.4);
        int b = t / M;
        const float* p = nx1 + (size_t)b * N * 3;
        float cx = nx2[t*3+0], cy = nx2[t*3+1], cz = nx2[t*3+2];
        int* out = gi2 + (size_t)t * K;
        int cnt = 0, first = 0;
        bool havefirst = false;
        for (int i = 0; i < N; ++i) {
            float dx = __fsub_rn(p[i*3+0], cx);
            float dy = __fsub_rn(p[i*3+1], cy);
            float dz = __fsub_rn(p[i*3+2], cz);
            float d  = __fadd_rn(__fadd_rn(__fmul_rn(dx,dx), __fmul_rn(dy,dy)),
                                 __fmul_rn(dz,dz));
            if (d <= r2) {
                if (!havefirst) { first = i; havefirst = true; }
                out[cnt++] = i;
                if (cnt == K) break;
            }
        }
        for (; cnt < K; ++cnt) out[cnt] = first;
        return;
    }
    // ---------------- mfma 64->64 role (CI=64, CO=64, NTILE=4, MROW=4)
    constexpr int CI = 64, CO = 64, KT = 2, NTILE = 4, MROW = 4;
    const int wid  = threadIdx.x >> 6;
    const int lane = threadIdx.x & 63;
    const int m    = lane & 15;
    const int kg   = lane >> 4;
    const int blockrow = blockIdx.x * (64 * MROW);
    bf16x8 Ahf[MROW * KT], Alf[MROW * KT];
    #pragma unroll
    for (int t = 0; t < MROW; ++t) {
        const us* arh = ah + (size_t)(blockrow + t*64 + wid*16 + m) * CI + kg * 8;
        const us* arl = al + (size_t)(blockrow + t*64 + wid*16 + m) * CI + kg * 8;
        #pragma unroll
        for (int kt = 0; kt < KT; ++kt) {
            Ahf[t*KT + kt] = *(const bf16x8*)(arh + kt*32);
            Alf[t*KT + kt] = *(const bf16x8*)(arl + kt*32);
        }
    }
    #pragma unroll
    for (int nt = 0; nt < NTILE; ++nt) {
        f32x4 acc[MROW];
        #pragma unroll
        for (int t = 0; t < MROW; ++t) acc[t] = (f32x4){0.f, 0.f, 0.f, 0.f};
        const us* wbh = wh + (size_t)(nt*16 + m) * CI + kg * 8;
        const us* wbl = wl + (size_t)(nt*16 + m) * CI + kg * 8;
        #pragma unroll
        for (int kt = 0; kt < KT; ++kt) {
            bf16x8 Bh = *(const bf16x8*)(wbh + kt*32);
            bf16x8 Bl = *(const bf16x8*)(wbl + kt*32);
            #pragma unroll
            for (int t = 0; t < MROW; ++t) {
                acc[t] = __builtin_amdgcn_mfma_f32_16x16x32_bf16(Ahf[t*KT+kt], Bh, acc[t], 0, 0, 0);
                acc[t] = __builtin_amdgcn_mfma_f32_16x16x32_bf16(Ahf[t*KT+kt], Bl, acc[t], 0, 0, 0);
                acc[t] = __builtin_amdgcn_mfma_f32_16x16x32_bf16(Alf[t*KT+kt], Bh, acc[t], 0, 0, 0);
            }
        }
        int dcol = nt*16 + m;
        float bv = bias[dcol];
        #pragma unroll
        for (int t = 0; t < MROW; ++t)
            #pragma unroll
            for (int r = 0; r < 4; ++r) {
                float v = fmaxf(acc[t][r] + bv, 0.f);
                size_t o = (size_t)(blockrow + t*64 + wid*16 + kg*4 + r) * CO + dcol;
                us h = f2bf(v);
                oh[o] = h;
                ol[o] = f2bf(v - bf2f(h));
            }
    }
}

// ---------------------------------------------------------------------------
// MFMA layer with column tiling + MROW row-tiles + NCOL column-pairing.
// OUTMODE: 0 = split-bf16 out (piggyback: zero ofp on last y-slice if set),
//          1 = fp32 out, 2 = maxpool(KPTS)->fp32,
//          3 = maxpool(KPTS)->split-bf16 (stride CO),
//          4 = maxpool(64)->split-bf16 into g3 (stride 288, col offset 3;
//              blockIdx.y==1 blocks fill g3 xyz/pad cols from ofp(=nx2)),
//          5 = per-block max(64 rows) -> atomicMax fp32 (batch = 128 rows).
// ---------------------------------------------------------------------------
template<int CI, int CO, int NTILE, int MROW, int KPTS, int OUTMODE, int NCOL>
__global__ __launch_bounds__(256) void mfma_layer_kernel(
    const us* __restrict__ ah, const us* __restrict__ al,
    const us* __restrict__ wh, const us* __restrict__ wl,
    const float* __restrict__ bias,
    us* __restrict__ oh, us* __restrict__ ol,
    float* __restrict__ ofp, int rowbase)
{
    constexpr int KT = CI / 32;
    static_assert(KT * MROW <= 18, "A-preload register budget");
    static_assert(NTILE % NCOL == 0, "column pairing");
    __shared__ float partial[4][OUTMODE >= 2 ? MROW : 1][OUTMODE >= 2 ? 16*NTILE : 1];

    if constexpr (OUTMODE == 0) {
        if (ofp != nullptr && blockIdx.y == gridDim.y - 1) {
            int i = (blockIdx.x * 256 + threadIdx.x) * 4;
            if (i < 32*1024) {
                ofp[i+0] = 0.f; ofp[i+1] = 0.f; ofp[i+2] = 0.f; ofp[i+3] = 0.f;
            }
            return;
        }
    }
    if constexpr (OUTMODE == 4) {
        if (blockIdx.y == 1) {
            int t = blockIdx.x * 256 + threadIdx.x;
            if (t < 4096 * 32) {
                int row = t >> 5, k = t & 31;
                float v = (k < 3) ? ofp[row*3 + k] : 0.f;
                int col = (k < 3) ? k : 259 + (k - 3);
                size_t o = (size_t)row * 288 + col;
                us h = f2bf(v);
                oh[o] = h; ol[o] = f2bf(v - bf2f(h));
            }
            return;
        }
    }

    const int wid  = threadIdx.x >> 6;
    const int lane = threadIdx.x & 63;
    const int m    = lane & 15;
    const int kg   = lane >> 4;
    const int blockrow = blockIdx.x * (64 * MROW);
    const int colbase  = blockIdx.y * (16 * NTILE);
    bf16x8 Ahf[MROW * KT], Alf[MROW * KT];
    #pragma unroll
    for (int t = 0; t < MROW; ++t) {
        const us* arh = ah + (size_t)(blockrow + t*64 + wid*16 + m) * CI + kg * 8;
        const us* arl = al + (size_t)(blockrow + t*64 + wid*16 + m) * CI + kg * 8;
        #pragma unroll
        for (int kt = 0; kt < KT; ++kt) {
            Ahf[t*KT + kt] = *(const bf16x8*)(arh + kt*32);
            Alf[t*KT + kt] = *(const bf16x8*)(arl + kt*32);
        }
    }
    #pragma unroll
    for (int ntg = 0; ntg < NTILE; ntg += NCOL) {
        f32x4 acc[MROW][NCOL];
        #pragma unroll
        for (int t = 0; t < MROW; ++t)
            #pragma unroll
            for (int c = 0; c < NCOL; ++c) acc[t][c] = (f32x4){0.f, 0.f, 0.f, 0.f};
        const us* wbh[NCOL];
        const us* wbl[NCOL];
        #pragma unroll
        for (int c = 0; c < NCOL; ++c) {
            wbh[c] = wh + (size_t)(colbase + (ntg + c)*16 + m) * CI + kg * 8;
            wbl[c] = wl + (size_t)(colbase + (ntg + c)*16 + m) * CI + kg * 8;
        }
        #pragma unroll
        for (int kt = 0; kt < KT; ++kt) {
            bf16x8 Bh[NCOL], Bl[NCOL];
            #pragma unroll
            for (int c = 0; c < NCOL; ++c) {
                Bh[c] = *(const bf16x8*)(wbh[c] + kt*32);
                Bl[c] = *(const bf16x8*)(wbl[c] + kt*32);
            }
            #pragma unroll
            for (int t = 0; t < MROW; ++t)
                #pragma unroll
                for (int c = 0; c < NCOL; ++c) {
                    acc[t][c] = __builtin_amdgcn_mfma_f32_16x16x32_bf16(Ahf[t*KT+kt], Bh[c], acc[t][c], 0, 0, 0);
                    acc[t][c] = __builtin_amdgcn_mfma_f32_16x16x32_bf16(Ahf[t*KT+kt], Bl[c], acc[t][c], 0, 0, 0);
                    acc[t][c] = __builtin_amdgcn_mfma_f32_16x16x32_bf16(Alf[t*KT+kt], Bh[c], acc[t][c], 0, 0, 0);
                }
        }
        #pragma unroll
        for (int c = 0; c < NCOL; ++c) {
            const int nt = ntg + c;
            int dcol = colbase + nt*16 + m;
            float bv = bias[dcol];
            #pragma unroll
            for (int t = 0; t < MROW; ++t) {
                float v[4];
                #pragma unroll
                for (int r = 0; r < 4; ++r) v[r] = fmaxf(acc[t][c][r] + bv, 0.f);
                if constexpr (OUTMODE == 0) {
                    #pragma unroll
                    for (int r = 0; r < 4; ++r) {
                        size_t o = (size_t)(blockrow + t*64 + wid*16 + kg*4 + r) * CO + dcol;
                        us h = f2bf(v[r]);
                        oh[o] = h;
                        ol[o] = f2bf(v[r] - bf2f(h));
                    }
                } else if constexpr (OUTMODE == 1) {
                    #pragma unroll
                    for (int r = 0; r < 4; ++r)
                        ofp[(size_t)(blockrow + t*64 + wid*16 + kg*4 + r) * CO + dcol] = v[r];
                } else {
                    float mx = fmaxf(fmaxf(v[0], v[1]), fmaxf(v[2], v[3]));
                    mx = fmaxf(mx, __shfl_xor(mx, 16));
                    mx = fmaxf(mx, __shfl_xor(mx, 32));
                    if (lane < 16) partial[wid][t][nt*16 + m] = mx;
                }
            }
        }
    }
    if constexpr (OUTMODE >= 2) {
        __syncthreads();
        for (int c = threadIdx.x; c < 16*NTILE; c += 256) {
            #pragma unroll
            for (int t = 0; t < MROW; ++t) {
                if constexpr (OUTMODE == 5) {
                    float mx = fmaxf(fmaxf(partial[0][t][c], partial[1][t][c]),
                                     fmaxf(partial[2][t][c], partial[3][t][c]));
                    int batch = (rowbase + blockrow + t*64) / 128;
                    atomicMax((int*)&ofp[(size_t)batch*CO + colbase + c],
                              __float_as_int(mx));
                } else if constexpr (KPTS == 64) {
                    float mx = fmaxf(fmaxf(partial[0][t][c], partial[1][t][c]),
                                     fmaxf(partial[2][t][c], partial[3][t][c]));
                    int cent = (rowbase + blockrow) / 64 + t;
                    if constexpr (OUTMODE == 2) {
                        ofp[(size_t)cent*CO + colbase + c] = mx;
                    } else if constexpr (OUTMODE == 4) {
                        size_t o = (size_t)cent*288 + 3 + colbase + c;
                        us h = f2bf(mx);
                        oh[o] = h; ol[o] = f2bf(mx - bf2f(h));
                    } else {
                        size_t o = (size_t)cent*CO + colbase + c;
                        us h = f2bf(mx);
                        oh[o] = h; ol[o] = f2bf(mx - bf2f(h));
                    }
                } else {               // KPTS == 32
                    int cent0 = (rowbase + blockrow) / 32 + t*2;
                    float v0 = fmaxf(partial[0][t][c], partial[1][t][c]);
                    float v1 = fmaxf(partial[2][t][c], partial[3][t][c]);
                    if constexpr (OUTMODE == 2) {
                        ofp[(size_t)cent0*CO + colbase + c]     = v0;
                        ofp[(size_t)(cent0+1)*CO + colbase + c] = v1;
                    } else {
                        size_t o0 = (size_t)cent0*CO + colbase + c;
                        size_t o1 = (size_t)(cent0+1)*CO + colbase + c;
                        us h0 = f2bf(v0), h1 = f2bf(v1);
                        oh[o0] = h0; ol[o0] = f2bf(v0 - bf2f(h0));
                        oh[o1] = h1; ol[o1] = f2bf(v1 - bf2f(h1));
                    }
                }
            }
        }
    }
}

// ---------------------------------------------------------------------------
// SA2 layer 1 as MFMA with per-lane GATHERED A rows (f1 split bf16) plus the
// 3-channel xyz part on the VALU in the epilogue.
// ---------------------------------------------------------------------------
template<int NTILE, int MROW>
__global__ __launch_bounds__(256) void mfma_sa2l1_kernel(
    const float* __restrict__ sxyz, const float* __restrict__ cxyz,
    const int* __restrict__ gi,
    const us* __restrict__ f1h, const us* __restrict__ f1l,
    const float* __restrict__ w,
    const us* __restrict__ wh, const us* __restrict__ wl,
    const float* __restrict__ bias,
    us* __restrict__ oh, us* __restrict__ ol,
    int rowbase)
{
    constexpr int CI = 128, CO = 128, KT = 4, KPTS = 64, M = 128, N = 512;
    const int wid  = threadIdx.x >> 6;
    const int lane = threadIdx.x & 63;
    const int m    = lane & 15;
    const int kg   = lane >> 4;
    const int blockrow = blockIdx.x * (64 * MROW);
    const int colbase  = blockIdx.y * (16 * NTILE);
    bf16x8 Ahf[MROW * KT], Alf[MROW * KT];
    #pragma unroll
    for (int t = 0; t < MROW; ++t) {
        int grow = rowbase + blockrow + t*64 + wid*16 + m;
        int cent = grow / KPTS;
        int b    = cent / M;
        int idx  = gi[grow];
        const us* arh = f1h + ((size_t)b*N + idx) * CI + kg * 8;
        const us* arl = f1l + ((size_t)b*N + idx) * CI + kg * 8;
        #pragma unroll
        for (int kt = 0; kt < KT; ++kt) {
            Ahf[t*KT + kt] = *(const bf16x8*)(arh + kt*32);
            Alf[t*KT + kt] = *(const bf16x8*)(arl + kt*32);
        }
    }
    float dx[MROW][4], dy[MROW][4], dz[MROW][4];
    #pragma unroll
    for (int t = 0; t < MROW; ++t)
        #pragma unroll
        for (int r = 0; r < 4; ++r) {
            int grow = rowbase + blockrow + t*64 + wid*16 + kg*4 + r;
            int cent = grow / KPTS;
            int b    = cent / M;
            int idx  = gi[grow];
            const float* pp = sxyz + ((size_t)b*N + idx)*3;
            const float* cc = cxyz + (size_t)cent*3;
            dx[t][r] = __fsub_rn(pp[0], cc[0]);
            dy[t][r] = __fsub_rn(pp[1], cc[1]);
            dz[t][r] = __fsub_rn(pp[2], cc[2]);
        }
    #pragma unroll
    for (int nt = 0; nt < NTILE; ++nt) {
        f32x4 acc[MROW];
        #pragma unroll
        for (int t = 0; t < MROW; ++t) acc[t] = (f32x4){0.f, 0.f, 0.f, 0.f};
        const us* wbh = wh + (size_t)(colbase + nt*16 + m) * CI + kg * 8;
        const us* wbl = wl + (size_t)(colbase + nt*16 + m) * CI + kg * 8;
        #pragma unroll
        for (int kt = 0; kt < KT; ++kt) {
            bf16x8 Bh = *(const bf16x8*)(wbh + kt*32);
            bf16x8 Bl = *(const bf16x8*)(wbl + kt*32);
            #pragma unroll
            for (int t = 0; t < MROW; ++t) {
                acc[t] = __builtin_amdgcn_mfma_f32_16x16x32_bf16(Ahf[t*KT+kt], Bh, acc[t], 0, 0, 0);
                acc[t] = __builtin_amdgcn_mfma_f32_16x16x32_bf16(Ahf[t*KT+kt], Bl, acc[t], 0, 0, 0);
                acc[t] = __builtin_amdgcn_mfma_f32_16x16x32_bf16(Alf[t*KT+kt], Bh, acc[t], 0, 0, 0);
            }
        }
        int dcol = colbase + nt*16 + m;
        float w0 = w[0*CO + dcol], w1 = w[1*CO + dcol], w2 = w[2*CO + dcol];
        float bv = bias[dcol];
        #pragma unroll
        for (int t = 0; t < MROW; ++t)
            #pragma unroll
            for (int r = 0; r < 4; ++r) {
                float v = acc[t][r] + bv + dx[t][r]*w0 + dy[t][r]*w1 + dz[t][r]*w2;
                v = fmaxf(v, 0.f);
                size_t o = (size_t)(blockrow + t*64 + wid*16 + kg*4 + r) * CO + dcol;
                us h = f2bf(v);
                oh[o] = h;
                ol[o] = f2bf(v - bf2f(h));
            }
    }
}

// ---------------------------------------------------------------------------
// Small-M FC GEMM: one thread per output element, no LDS, no barriers.
// ---------------------------------------------------------------------------
template<int RELU, int HASB>
__global__ __launch_bounds__(256) void fc_kernel(
    const float* __restrict__ A, const float* __restrict__ W,
    const float* __restrict__ bias, float* __restrict__ Cc,
    int Mr, int Nc, int Kd)
{
    int t = blockIdx.x * 256 + threadIdx.x;
    if (t >= Mr * Nc) return;
    int row = t / Nc, col = t % Nc;
    const float* a = A + (size_t)row * Kd;
    const float* w = W + col;
    float acc = 0.f;
    #pragma unroll 8
    for (int k = 0; k < Kd; ++k)
        acc += a[k] * w[(size_t)k * Nc];
    if (HASB) acc += bias[col];
    if (RELU) acc = fmaxf(acc, 0.f);
    Cc[t] = acc;
}

// ---------------------------------------------------------------------------
extern "C" void kernel_launch(void* const* d_in, const int* in_sizes, int n_in,
                              void* d_out, int out_size, void* d_ws, size_t ws_size,
                              hipStream_t stream)
{
    const float* xyz    = (const float*)d_in[0];
    const float* points = (const float*)d_in[1];
    const float* w1a = (const float*)d_in[2];  const float* b1a = (const float*)d_in[3];
    const float* w1b = (const float*)d_in[4];  const float* b1b = (const float*)d_in[5];
    const float* w1c = (const float*)d_in[6];  const float* b1c = (const float*)d_in[7];
    const float* w2a = (const float*)d_in[8];  const float* b2a = (const float*)d_in[9];
    const float* w2b = (const float*)d_in[10]; const float* b2b = (const float*)d_in[11];
    const float* w2c = (const float*)d_in[12]; const float* b2c = (const float*)d_in[13];
    const float* w3a = (const float*)d_in[14]; const float* b3a = (const float*)d_in[15];
    const float* w3b = (const float*)d_in[16]; const float* b3b = (const float*)d_in[17];
    const float* w3c = (const float*)d_in[18]; const float* b3c = (const float*)d_in[19];
    const float* lin1 = (const float*)d_in[20];
    const float* lin2 = (const float*)d_in[21];
    const float* clsw = (const float*)d_in[22];
    const float* clsb = (const float*)d_in[23];

    char* ws = (char*)d_ws;
    size_t off = 0;
    auto alloc = [&](size_t bytes) -> void* {
        void* p = ws + off;
        off += (bytes + 255) & ~(size_t)255;
        return p;
    };
    int*   fps1 = (int*)  alloc((size_t)32*512*4);
    float* nx1  = (float*)alloc((size_t)32*512*3*4);
    int*   gi1  = (int*)  alloc((size_t)32*512*32*4);
    int*   fps2 = (int*)  alloc((size_t)32*128*4);
    float* nx2  = (float*)alloc((size_t)32*128*3*4);
    int*   gi2  = (int*)  alloc((size_t)32*128*64*4);
    float* f3   = (float*)alloc((size_t)32*1024*4);
    float* fc1  = (float*)alloc((size_t)32*512*4);
    float* fc2  = (float*)alloc((size_t)32*256*4);

    // split weights (transposed [CO][CIpad], bf16 hi/lo)
    us* w1bh = (us*)alloc(64*64*2);     us* w1bl = (us*)alloc(64*64*2);
    us* w1ch = (us*)alloc(128*64*2);    us* w1cl = (us*)alloc(128*64*2);
    us* w2ah = (us*)alloc(128*128*2);   us* w2al = (us*)alloc(128*128*2);   // feats rows 3..130
    us* w2bh = (us*)alloc(128*128*2);   us* w2bl = (us*)alloc(128*128*2);
    us* w2ch = (us*)alloc(256*128*2);   us* w2cl = (us*)alloc(256*128*2);
    us* w3ah = (us*)alloc(256*288*2);   us* w3al = (us*)alloc(256*288*2);   // padded 259->288
    us* w3bh = (us*)alloc(512*256*2);   us* w3bl = (us*)alloc(512*256*2);
    us* w3ch = (us*)alloc(1024*512*2);  us* w3cl = (us*)alloc(1024*512*2);
    // SA1 output (split) = SA2 input feats (L2/L3-resident, 8.4 MB)
    us* f1h  = (us*)alloc((size_t)16384*128*2);
    us* f1l  = (us*)alloc((size_t)16384*128*2);
    // SA3 activations
    us* g3H  = (us*)alloc((size_t)4096*288*2);  us* g3L  = (us*)alloc((size_t)4096*288*2);
    us* h3aH = (us*)alloc((size_t)4096*256*2);  us* h3aL = (us*)alloc((size_t)4096*256*2);
    us* h3bH = (us*)alloc((size_t)4096*512*2);  us* h3bL = (us*)alloc((size_t)4096*512*2);

    // big split activation ping-pong buffers (hi/lo per side)
    size_t avail = (ws_size > off + 1024) ? (ws_size - off - 1024) : 0;
    size_t bufcap = avail / 4;
    if (bufcap > (size_t)67200000) bufcap = 67200000;   // 524288 rows x 64ch x 2B
    us* Ah = (us*)alloc(bufcap); us* Al = (us*)alloc(bufcap);
    us* Bh = (us*)alloc(bufcap); us* Bl = (us*)alloc(bufcap);

    // ---- weight-prep job table (runs as piggyback blocks inside fps1 launch)
    WJobs jobs;
    {
        const float* src[8] = { w1b, w1c, w2a, w2b, w2c, w3a, w3b, w3c };
        us* wh[8] = { w1bh, w1ch, w2ah, w2bh, w2ch, w3ah, w3bh, w3ch };
        us* wl[8] = { w1bl, w1cl, w2al, w2bl, w2cl, w3al, w3bl, w3cl };
        int CItot[8] = { 64, 64, 131, 128, 128, 259, 256, 512 };
        int CO[8]    = { 64, 128, 128, 128, 256, 256, 512, 1024 };
        int CIpad[8] = { 64, 64, 128, 128, 128, 288, 256, 512 };
        int ro[8]    = { 0, 0, 3, 0, 0, 0, 0, 0 };
        int cum = 0;
        for (int j = 0; j < 8; ++j) {
            jobs.src[j] = src[j]; jobs.wh[j] = wh[j]; jobs.wl[j] = wl[j];
            jobs.CItot[j] = CItot[j]; jobs.CO[j] = CO[j];
            jobs.CIpad[j] = CIpad[j]; jobs.ro[j] = ro[j];
            jobs.blk_off[j] = cum;
            cum += ceil_div(CIpad[j] * CO[j], 256);
        }
        jobs.blk_off[8] = cum;
    }

    // ---- SA1: N=1024 -> M=512, r=0.2, K=32, MLP 6->64->64->128
    fps4_wprep_kernel<1024><<<32 + jobs.blk_off[8], 256, 0, stream>>>(
        xyz, 512, fps1, nx1, 32, jobs);
    ballquery_kernel<<<ceil_div(32*512, 256), 256, 0, stream>>>(
        xyz, nx1, gi1, 32, 1024, 512, 32, (float)(0.2*0.2));
    {
        const int rows = 32*512*32;                     // 524288
        int ch = (int)((bufcap / (64*2)) & ~(size_t)1023);
        if (ch > rows) ch = rows;
        if (ch < 1024) ch = 1024;
        int first = 1;
        for (int r0 = 0; r0 < rows; r0 += ch) {
            int rc = rows - r0 < ch ? rows - r0 : ch;
            int nb1 = rc/64, nb2 = rc/256;
            sa1_l1_fps2_kernel<<<nb1 + (first ? 32 : 0), 256, 0, stream>>>(
                xyz, points, nx1, gi1, w1a, b1a, Ah, Al, r0, nb1, first, fps2, nx2);
            sa1_l2_bq2_kernel<<<nb2 + (first ? 16 : 0), 256, 0, stream>>>(
                Ah, Al, w1bh, w1bl, b1b, Bh, Bl, nb2, first, nx1, nx2, gi2);
            mfma_layer_kernel<64, 128, 8, 4, 32, 3, 1><<<dim3(nb2, 1), 256, 0, stream>>>(
                Bh, Bl, w1ch, w1cl, b1c, f1h, f1l, nullptr, r0);
            first = 0;
        }
    }

    // ---- SA2: N=512 -> M=128, r=0.4, K=64, MLP 131->128->128->256
    //      (L3 writes split-bf16 directly into g3; y=1 slice fills xyz/pad)
    {
        const int rows = 32*128*64;                     // 262144
        int ch = (int)((bufcap / (128*2)) & ~(size_t)1023);
        if (ch > rows) ch = rows;
        if (ch < 1024) ch = 1024;
        for (int r0 = 0; r0 < rows; r0 += ch) {
            int rc = rows - r0 < ch ? rows - r0 : ch;
            mfma_sa2l1_kernel<8, 2><<<dim3(rc/128, 1), 256, 0, stream>>>(
                nx1, nx2, gi2, f1h, f1l, w2a, w2ah, w2al, b2a, Ah, Al, r0);
            mfma_layer_kernel<128, 128, 8, 4, 0, 0, 1><<<dim3(rc/256, 1), 256, 0, stream>>>(
                Ah, Al, w2bh, w2bl, b2b, Bh, Bl, nullptr, 0);
            mfma_layer_kernel<128, 256, 16, 4, 64, 4, 1><<<dim3(rc/256, 2), 256, 0, stream>>>(
                Bh, Bl, w2ch, w2cl, b2c, g3H, g3L, (float*)nx2, r0);
        }
    }

    // ---- SA3 (group_all): g3 [4096][288] -> 288->256 -> 256->512 (zeroes f3
    //      on extra y-slice) -> 512->1024 + fused atomicMax rowmax -> f3
    mfma_layer_kernel<288, 256, 2, 1, 0, 0, 2><<<dim3(4096/64, 256/32), 256, 0, stream>>>(
        g3H, g3L, w3ah, w3al, b3a, h3aH, h3aL, nullptr, 0);
    mfma_layer_kernel<256, 512, 2, 2, 0, 0, 2><<<dim3(4096/128, 512/32 + 1), 256, 0, stream>>>(
        h3aH, h3aL, w3bh, w3bl, b3b, h3bH, h3bL, f3, 0);
    mfma_layer_kernel<512, 1024, 4, 1, 0, 5, 2><<<dim3(4096/64, 1024/64), 256, 0, stream>>>(
        h3bH, h3bL, w3ch, w3cl, b3c, nullptr, nullptr, f3, 0);

    // ---- FC head (fp32, thread-per-output latency-optimized)
    fc_kernel<1,0><<<ceil_div(32*512, 256), 256, 0, stream>>>(
        f3, lin1, nullptr, fc1, 32, 512, 1024);
    fc_kernel<1,0><<<ceil_div(32*256, 256), 256, 0, stream>>>(
        fc1, lin2, nullptr, fc2, 32, 256, 512);
    fc_kernel<0,1><<<ceil_div(32*40, 256), 256, 0, stream>>>(
        fc2, clsw, clsb, (float*)d_out, 32, 40, 256);
}